// Round 16
// baseline (456.878 us; speedup 1.0000x reference)
//
#include <hip/hip_runtime.h>
#include <math.h>

#define NN 100000      // nodes per type
#define EE 200000      // edges per relation
#define HH 4
#define DD 128
#define HD 512         // H*D
#define KIN 256        // input feature dim
#define LN_EPS 1e-5f
#define SLOPE 0.2f
#define NB_SCAN 98     // ceil(NN/1024)

// LDS bank-conflict swizzle for the Cs[2048] table (skinny8 fallback).
#define CSW(a) ((a) ^ (((a) >> 5) & 31))

typedef short bf16x8 __attribute__((ext_vector_type(8)));
typedef unsigned short u16x4 __attribute__((ext_vector_type(4)));
typedef float f32x4 __attribute__((ext_vector_type(4)));

typedef __attribute__((address_space(3))) unsigned int lds_uint;
typedef const __attribute__((address_space(1))) unsigned int glb_uint;

static __device__ __forceinline__ void gload_lds16(const void* g, void* l) {
  __builtin_amdgcn_global_load_lds((glb_uint*)g, (lds_uint*)l, 16, 0, 0);
}

static __device__ __forceinline__ unsigned short f2bf(float x) {
  unsigned int u = __float_as_uint(x);
  u += 0x7fffu + ((u >> 16) & 1u);   // RNE
  return (unsigned short)(u >> 16);
}
static __device__ __forceinline__ float bf_lo(unsigned int u) {
  return __uint_as_float(u << 16);
}
static __device__ __forceinline__ float bf_hi(unsigned int u) {
  return __uint_as_float(u & 0xffff0000u);
}

// Branch-free erf, Abramowitz-Stegun 7.1.26 (max err 1.5e-7).
static __device__ __forceinline__ float erf_fast(float x) {
  float ax = fabsf(x);
  float t = __builtin_amdgcn_rcpf(fmaf(0.3275911f, ax, 1.0f));
  float p = fmaf(1.061405429f, t, -1.453152027f);
  p = fmaf(p, t, 1.421413741f);
  p = fmaf(p, t, -0.284496736f);
  p = fmaf(p, t, 0.254829592f);
  p = p * t;
  float r = 1.0f - p * __expf(-ax * ax);
  return copysignf(r, x);
}
static __device__ __forceinline__ float gelu_fast(float y) {
  return 0.5f * y * (1.0f + erf_fast(y * 0.70710678118f));
}

// ---------------- convert + transpose weights to bf16 [N][K]
__global__ __launch_bounds__(256) void convw(
    const float* __restrict__ W1, const float* __restrict__ W2,
    const float* __restrict__ pWh, const float* __restrict__ pWf,
    short* __restrict__ W1t, short* __restrict__ W2t,
    short* __restrict__ pWht, short* __restrict__ pWft) {
  int idx = blockIdx.x * 256 + threadIdx.x;
  if (idx < 512 * 256) {
    int n = idx >> 8, k = idx & 255;
    W1t[idx] = (short)f2bf(W1[(size_t)k * HD + n]);
    W2t[idx] = (short)f2bf(W2[(size_t)k * HD + n]);
  }
  if (idx < 128 * 256) {
    int n = idx >> 8, k = idx & 255;
    pWht[idx] = (short)f2bf(pWh[(size_t)k * DD + n]);
    pWft[idx] = (short)f2bf(pWf[(size_t)k * DD + n]);
  }
}

// ---------------- build C[k,h] = sum_d W[k,h*128+d]*a[h*128+d]  (f32 + bf16 Ct)
__global__ __launch_bounds__(256) void make_c(
    const float* __restrict__ W1, const float* __restrict__ al1, const float* __restrict__ ar1,
    const float* __restrict__ W2, const float* __restrict__ al2, const float* __restrict__ ar2,
    float* __restrict__ Cout, short* __restrict__ CtH, short* __restrict__ CtF) {
  int which = blockIdx.y;
  const float* W = (which < 2) ? W1 : W2;
  const float* a = (which == 0) ? al1 : (which == 1) ? ar1 : (which == 2) ? al2 : ar2;
  int k = threadIdx.x;
  float* C = Cout + (size_t)which * 1024;
#pragma unroll
  for (int h = 0; h < HH; h++) {
    float s = 0.f;
    for (int d = 0; d < DD; d++) s = fmaf(W[(size_t)k * HD + h * DD + d], a[h * DD + d], s);
    C[k * HH + h] = s;
    short b = (short)f2bf(s);
    if (which == 0)      CtH[h * KIN + k] = b;
    else if (which == 3) CtH[(4 + h) * KIN + k] = b;
    else if (which == 1) CtF[h * KIN + k] = b;
    else                 CtF[(4 + h) * KIN + k] = b;
  }
  if (which == 0) {
#pragma unroll
    for (int j = 0; j < 8; j++) CtH[(8 + j) * KIN + k] = 0;
  } else if (which == 1) {
#pragma unroll
    for (int j = 0; j < 8; j++) CtF[(8 + j) * KIN + k] = 0;
  }
}

// ---------------- bm1[d] = 0.25*sum_h b1 + pbf ; bm2 likewise (b2, pbh)
__global__ __launch_bounds__(256) void make_bm(
    const float* __restrict__ b1, const float* __restrict__ pbf,
    const float* __restrict__ b2, const float* __restrict__ pbh,
    float* __restrict__ bm) {
  int d = threadIdx.x;
  if (d < 128) {
    bm[d] = 0.25f * (b1[d] + b1[128 + d] + b1[256 + d] + b1[384 + d]) + pbf[d];
  } else {
    int dd = d - 128;
    bm[d] = 0.25f * (b2[dd] + b2[128 + dd] + b2[256 + dd] + b2[384 + dd]) + pbh[dd];
  }
}

// ---------------- fused bf16 convert + el/er dots via MFMA, coalesced + deep ILP
// Stage 1a: ALL 16 float4 loads issued into regs (coalesced, 16 in flight).
// Stage 1b: convert + Xb store + swizzled LDS fill. Stage 2: MFMA. Epilogue: coalesced.
__global__ __launch_bounds__(256) void prep_mfma(
    const float* __restrict__ XH, const float* __restrict__ XF,
    const short* __restrict__ CtH, const short* __restrict__ CtF,
    short* __restrict__ XbH, short* __restrict__ XbF,
    float* __restrict__ o1H, float* __restrict__ o2H,
    float* __restrict__ o1F, float* __restrict__ o2F, int M) {
  __shared__ short Asm[64 * 256];   // 32 KB bf16 tile
  __shared__ float os[64 * 8];      // 2 KB acc staging
  int which = blockIdx.y;
  const float* X = which ? XF : XH;
  const short* Ct = which ? CtF : CtH;
  short* Xb = which ? XbF : XbH;
  float* o1 = which ? o1F : o1H;
  float* o2 = which ? o2F : o2H;
  int t = threadIdx.x, lane = t & 63, wid = t >> 6;
  int row0 = blockIdx.x * 64;

  // ---- stage 1a: issue all loads (coalesced; statically-indexed regs)
  int rsub = t >> 5;            // 0..7 row within the 8-row slice
  int c16 = t & 31;             // 16B chunk index within the row
  float4 va[8], vb[8];
#pragma unroll
  for (int i = 0; i < 8; i++) {
    int r_loc = i * 8 + rsub;
    int grow = row0 + r_loc; if (grow > M - 1) grow = M - 1;
    const float* xp = X + (size_t)grow * KIN + c16 * 8;
    va[i] = *(const float4*)xp;
    vb[i] = *(const float4*)(xp + 4);
  }
  // ---- stage 1b: convert + store (global Xb + swizzled LDS)
#pragma unroll
  for (int i = 0; i < 8; i++) {
    int r_loc = i * 8 + rsub;
    int grow = row0 + r_loc; if (grow > M - 1) grow = M - 1;
    float4 v0 = va[i], v1 = vb[i];
    bf16x8 af;
    af[0] = (short)f2bf(v0.x); af[1] = (short)f2bf(v0.y);
    af[2] = (short)f2bf(v0.z); af[3] = (short)f2bf(v0.w);
    af[4] = (short)f2bf(v1.x); af[5] = (short)f2bf(v1.y);
    af[6] = (short)f2bf(v1.z); af[7] = (short)f2bf(v1.w);
    *(bf16x8*)(Xb + (size_t)grow * KIN + c16 * 8) = af;   // coalesced (dup rows benign)
    int swc = c16 ^ (r_loc & 7);                          // swizzled 16B chunk
    *(bf16x8*)((char*)Asm + r_loc * 512 + swc * 16) = af;
  }
  // B fragments (global, L2-hot)
  int lr = lane & 15, lk = lane >> 4;
  bf16x8 bfrag[8];
#pragma unroll
  for (int kc = 0; kc < 8; kc++)
    bfrag[kc] = *(const bf16x8*)(Ct + lr * KIN + kc * 32 + lk * 8);
  __syncthreads();

  // ---- stage 2: MFMA per wave over rows wid*16..+16
  {
    int lrow = wid * 16 + lr;
    f32x4 acc = (f32x4){0.f, 0.f, 0.f, 0.f};
#pragma unroll
    for (int kc = 0; kc < 8; kc++) {
      int chunk = (lk + kc * 4) ^ (lrow & 7);
      bf16x8 af = *(bf16x8*)((char*)Asm + lrow * 512 + chunk * 16);
      acc = __builtin_amdgcn_mfma_f32_16x16x32_bf16(af, bfrag[kc], acc, 0, 0, 0);
    }
    if (lr < 8) {
#pragma unroll
      for (int r = 0; r < 4; r++)
        os[(wid * 16 + lk * 4 + r) * 8 + lr] = acc[r];
    }
  }
  __syncthreads();

  // ---- epilogue: coalesced o1/o2 writes
  if (t < 64) {
    int row = row0 + t;
    if (row < M)
      *(float4*)(o1 + (size_t)row * HH) =
          make_float4(os[t * 8 + 0], os[t * 8 + 1], os[t * 8 + 2], os[t * 8 + 3]);
  } else if (t < 128) {
    int j = t - 64;
    int row = row0 + j;
    if (row < M)
      *(float4*)(o2 + (size_t)row * HH) =
          make_float4(os[j * 8 + 4], os[j * 8 + 5], os[j * 8 + 6], os[j * 8 + 7]);
  }
}

// ---------------- fallback skinny (no bf16 feature copy)
__global__ __launch_bounds__(256) void skinny8(
    const float* __restrict__ X, const float* __restrict__ C1, const float* __restrict__ C2,
    float* __restrict__ o1, float* __restrict__ o2, int M) {
  __shared__ float Cs[KIN * 8];
  int tid = threadIdx.x;
  for (int i = tid; i < KIN * 4; i += 256) {
    int k = i >> 2, h = i & 3;
    Cs[CSW(k * 8 + h)] = C1[i];
    Cs[CSW(k * 8 + 4 + h)] = C2[i];
  }
  __syncthreads();
  int wave = tid >> 6, lane = tid & 63;
  int n = blockIdx.x * 4 + wave;
  if (n >= M) return;
  float4 xv = ((const float4*)(X + (size_t)n * KIN))[lane];
  float xs[4] = {xv.x, xv.y, xv.z, xv.w};
  float acc[8] = {0.f, 0.f, 0.f, 0.f, 0.f, 0.f, 0.f, 0.f};
#pragma unroll
  for (int j = 0; j < 4; j++) {
    int k = lane * 4 + j;
#pragma unroll
    for (int t = 0; t < 8; t++) acc[t] = fmaf(xs[j], Cs[CSW(k * 8 + t)], acc[t]);
  }
#pragma unroll
  for (int off = 32; off >= 1; off >>= 1)
#pragma unroll
    for (int t = 0; t < 8; t++) acc[t] += __shfl_xor(acc[t], off);
  if (lane == 0) {
#pragma unroll
    for (int h = 0; h < HH; h++) {
      o1[(size_t)n * HH + h] = acc[h];
      o2[(size_t)n * HH + h] = acc[4 + h];
    }
  }
}

// ---------------- CSR build ----------------
__global__ __launch_bounds__(256) void hist2(
    const int* __restrict__ d1, const int* __restrict__ d2,
    int* __restrict__ c1, int* __restrict__ c2) {
  int gid = blockIdx.x * 256 + threadIdx.x;
  if (gid < EE) atomicAdd(&c1[d1[gid]], 1);
  else if (gid < 2 * EE) atomicAdd(&c2[d2[gid - EE]], 1);
}

__global__ __launch_bounds__(256) void scan_chunk(
    const int* __restrict__ c1, const int* __restrict__ c2,
    int* __restrict__ rp1, int* __restrict__ rp2, int* __restrict__ bsum) {
  int rel = blockIdx.y;
  const int* counts = rel ? c2 : c1;
  int* rowptr = rel ? rp2 : rp1;
  int* bs = bsum + rel * 128;
  __shared__ int sd[256];
  int tid = threadIdx.x;
  int base = blockIdx.x * 1024 + tid * 4;
  int c[4];
#pragma unroll
  for (int j = 0; j < 4; j++) c[j] = (base + j < NN) ? counts[base + j] : 0;
  int tot = c[0] + c[1] + c[2] + c[3];
  sd[tid] = tot; __syncthreads();
  for (int o = 1; o < 256; o <<= 1) {
    int v = (tid >= o) ? sd[tid - o] : 0;
    __syncthreads();
    sd[tid] += v;
    __syncthreads();
  }
  int excl = sd[tid] - tot;
  int run = excl;
#pragma unroll
  for (int j = 0; j < 4; j++) {
    if (base + j < NN) rowptr[base + j] = run;
    run += c[j];
  }
  if (tid == 255) bs[blockIdx.x] = sd[255];
}

__global__ __launch_bounds__(128) void scan_bsum(int* __restrict__ bsum) {
  int rel = blockIdx.y;
  int* bs = bsum + rel * 128;
  __shared__ int sd[128];
  int tid = threadIdx.x;
  int v = (tid < NB_SCAN) ? bs[tid] : 0;
  sd[tid] = v; __syncthreads();
  for (int o = 1; o < 128; o <<= 1) {
    int t = (tid >= o) ? sd[tid - o] : 0;
    __syncthreads();
    sd[tid] += t;
    __syncthreads();
  }
  bs[tid] = sd[tid] - v;
}

__global__ __launch_bounds__(256) void addoff2(
    int* __restrict__ rp1, int* __restrict__ rp2,
    int* __restrict__ cur1, int* __restrict__ cur2,
    const int* __restrict__ bsum) {
  int rel = blockIdx.y;
  int* rowptr = rel ? rp2 : rp1;
  int* cur = rel ? cur2 : cur1;
  const int* bs = bsum + rel * 128;
  int i = blockIdx.x * 256 + threadIdx.x;
  if (i < NN) {
    int r = rowptr[i] + bs[i >> 10];
    rowptr[i] = r;
    cur[i] = r;
  }
  if (i == 0) rowptr[NN] = EE;
}

// ---------------- fill CSR: src id + per-edge exp coeffs (NO denominator atomics)
__global__ __launch_bounds__(256) void fill_s(
    const int* __restrict__ e1s, const int* __restrict__ e1d,
    const int* __restrict__ e2s, const int* __restrict__ e2d,
    const float* __restrict__ el1, const float* __restrict__ er1,
    const float* __restrict__ el2, const float* __restrict__ er2,
    int* __restrict__ cur1, int* __restrict__ cur2,
    int* __restrict__ adj1, int* __restrict__ adj2,
    float* __restrict__ wexp1, float* __restrict__ wexp2) {
  int gid = blockIdx.x * 256 + threadIdx.x;
  int rel = (gid >= EE);
  if (gid >= 2 * EE) return;
  int e = rel ? gid - EE : gid;
  const int* srcp = rel ? e2s : e1s;
  const int* dstp = rel ? e2d : e1d;
  const float* el = rel ? el2 : el1;
  const float* er = rel ? er2 : er1;
  int* cur = rel ? cur2 : cur1;
  int* adj = rel ? adj2 : adj1;
  float* wexp = rel ? wexp2 : wexp1;
  int si = srcp[e], di = dstp[e];
  int p = atomicAdd(&cur[di], 1);
  adj[p] = si;
  float4 l = *(const float4*)(el + (size_t)si * HH);
  float4 r = *(const float4*)(er + (size_t)di * HH);
  float v0 = l.x + r.x, v1 = l.y + r.y, v2 = l.z + r.z, v3 = l.w + r.w;
  v0 = v0 > 0.f ? v0 : SLOPE * v0; v1 = v1 > 0.f ? v1 : SLOPE * v1;
  v2 = v2 > 0.f ? v2 : SLOPE * v2; v3 = v3 > 0.f ? v3 : SLOPE * v3;
  *(float4*)(wexp + (size_t)p * HH) =
      make_float4(__expf(v0), __expf(v1), __expf(v2), __expf(v3));
}

// ---------------- MFMA GEMM: C[M x N] = A[M x 256] @ Wt[N x 256]^T
template <int ABF>
__global__ __launch_bounds__(256) void mfma_gemm(
    const void* __restrict__ Av, const short* __restrict__ Wt,
    void* __restrict__ Cout, int ldC, int M, int write_bf, int ncol) {
  __shared__ short As[128 * 64];
  __shared__ short Bs[128 * 64];
  int nwg = gridDim.x;
  int q = nwg >> 3, r = nwg & 7;
  int xcd = blockIdx.x & 7, seq = blockIdx.x >> 3;
  int lid = (xcd < r) ? (xcd * (q + 1) + seq) : (r * (q + 1) + (xcd - r) * q + seq);
  int row0 = (lid / ncol) * 128;
  int col0 = (lid % ncol) * 128;

  int tid = threadIdx.x;
  int lane = tid & 63, wid = tid >> 6;
  int wm = wid >> 1, wn = wid & 1;

  f32x4 acc[4][4];
#pragma unroll
  for (int i = 0; i < 4; i++)
#pragma unroll
    for (int j = 0; j < 4; j++) acc[i][j] = (f32x4){0.f, 0.f, 0.f, 0.f};

  int am = tid >> 1;
  int akh = (tid & 1) * 32;
  bool arow_ok = (row0 + am) < M;

  for (int k0 = 0; k0 < KIN; k0 += 64) {
    __syncthreads();
    if (ABF) {
      int rr8 = lane >> 3;
      int bby = (lane & 7) * 16;
#pragma unroll
      for (int c2 = 0; c2 < 4; c2++) {
        int rr = wid * 32 + c2 * 8 + rr8;
        int rg = row0 + rr; if (rg > M - 1) rg = M - 1;
        int sb = bby ^ ((rr & 7) << 4);
        gload_lds16((const char*)Av + (size_t)rg * (KIN * 2) + k0 * 2 + sb,
                    (char*)As + wid * 4096 + c2 * 1024);
      }
#pragma unroll
      for (int c2 = 0; c2 < 4; c2++) {
        int rr = wid * 32 + c2 * 8 + rr8;
        int sb = bby ^ ((rr & 7) << 4);
        gload_lds16((const char*)Wt + (size_t)(col0 + rr) * (KIN * 2) + k0 * 2 + sb,
                    (char*)Bs + wid * 4096 + c2 * 1024);
      }
    } else {
      const float* xp = (const float*)Av + (size_t)(row0 + am) * KIN + k0 + akh;
#pragma unroll
      for (int c = 0; c < 4; c++) {
        float4 v0, v1;
        if (arow_ok) {
          v0 = *(const float4*)(xp + c * 8);
          v1 = *(const float4*)(xp + c * 8 + 4);
        } else {
          v0 = make_float4(0.f, 0.f, 0.f, 0.f);
          v1 = v0;
        }
        bf16x8 pk;
        pk[0] = (short)f2bf(v0.x); pk[1] = (short)f2bf(v0.y);
        pk[2] = (short)f2bf(v0.z); pk[3] = (short)f2bf(v0.w);
        pk[4] = (short)f2bf(v1.x); pk[5] = (short)f2bf(v1.y);
        pk[6] = (short)f2bf(v1.z); pk[7] = (short)f2bf(v1.w);
        int kc = akh + c * 8;
        int ad = (am * 128 + kc * 2) ^ ((am & 7) << 4);
        *(bf16x8*)((char*)As + ad) = pk;
      }
      int bn = tid >> 1;
      int bkh = (tid & 1) * 32;
      const short* wp = Wt + (size_t)(col0 + bn) * KIN + k0 + bkh;
#pragma unroll
      for (int c = 0; c < 4; c++) {
        bf16x8 pv = *(const bf16x8*)(wp + c * 8);
        int kc = bkh + c * 8;
        int bd = (bn * 128 + kc * 2) ^ ((bn & 7) << 4);
        *(bf16x8*)((char*)Bs + bd) = pv;
      }
    }
    __syncthreads();
#pragma unroll
    for (int ks = 0; ks < 2; ks++) {
      int kb = ks * 32 + (lane >> 4) * 8;
      bf16x8 af[4], bfv[4];
#pragma unroll
      for (int mf = 0; mf < 4; mf++) {
        int rr = wm * 64 + mf * 16 + (lane & 15);
        int ad = (rr * 128 + kb * 2) ^ ((rr & 7) << 4);
        af[mf] = *(bf16x8*)((char*)As + ad);
      }
#pragma unroll
      for (int nf = 0; nf < 4; nf++) {
        int cc = wn * 64 + nf * 16 + (lane & 15);
        int bd = (cc * 128 + kb * 2) ^ ((cc & 7) << 4);
        bfv[nf] = *(bf16x8*)((char*)Bs + bd);
      }
#pragma unroll
      for (int mf = 0; mf < 4; mf++)
#pragma unroll
        for (int nf = 0; nf < 4; nf++)
          acc[mf][nf] = __builtin_amdgcn_mfma_f32_16x16x32_bf16(af[mf], bfv[nf], acc[mf][nf], 0, 0, 0);
    }
  }
  int lr = lane >> 4, lc = lane & 15;
#pragma unroll
  for (int mf = 0; mf < 4; mf++) {
#pragma unroll
    for (int r4 = 0; r4 < 4; r4++) {
      int row = row0 + wm * 64 + mf * 16 + lr * 4 + r4;
      if (row < M) {
#pragma unroll
        for (int nf = 0; nf < 4; nf++) {
          int col = col0 + wn * 64 + nf * 16 + lc;
          float v = acc[mf][nf][r4];
          if (write_bf) ((unsigned short*)Cout)[(size_t)row * ldC + col] = f2bf(v);
          else ((float*)Cout)[(size_t)row * ldC + col] = v;
        }
      }
    }
  }
}

// ---------------- single-pass agg + mean + residual + LN + GELU (one wave/dst)
__global__ __launch_bounds__(256) void agg2(
    const int* __restrict__ rowptr, const int* __restrict__ adj,
    const float* __restrict__ wexp,
    const unsigned short* __restrict__ fsb,
    const float* __restrict__ bm,
    const float* __restrict__ g, const float* __restrict__ be,
    float* __restrict__ out, int M) {
  int wave = threadIdx.x >> 6, lane = threadIdx.x & 63;
  int n = blockIdx.x * 4 + wave;
  if (n >= M) return;
  int beg = rowptr[n], end = rowptr[n + 1];
  int lh = lane >> 4, lc = lane & 15;
  float sh = 0.f;
  float m[8] = {0.f, 0.f, 0.f, 0.f, 0.f, 0.f, 0.f, 0.f};
  for (int t = beg; t < end; t++) {
    int si = adj[t];
    float wh = wexp[(size_t)t * HH + lh];
    sh += wh;
    uint4 u = *(const uint4*)(fsb + (size_t)si * HD + lane * 8);
    m[0] = fmaf(wh, bf_lo(u.x), m[0]); m[1] = fmaf(wh, bf_hi(u.x), m[1]);
    m[2] = fmaf(wh, bf_lo(u.y), m[2]); m[3] = fmaf(wh, bf_hi(u.y), m[3]);
    m[4] = fmaf(wh, bf_lo(u.z), m[4]); m[5] = fmaf(wh, bf_hi(u.z), m[5]);
    m[6] = fmaf(wh, bf_lo(u.w), m[6]); m[7] = fmaf(wh, bf_hi(u.w), m[7]);
  }
  float rsh = sh > 0.f ? 0.25f / sh : 0.f;
#pragma unroll
  for (int j = 0; j < 8; j++) m[j] *= rsh;
#pragma unroll
  for (int j = 0; j < 8; j++) {
    m[j] += __shfl_xor(m[j], 16);
    m[j] += __shfl_xor(m[j], 32);
  }
  const float4* bmp = (const float4*)(bm + lc * 8);
  float4 b0 = bmp[0], b1 = bmp[1];
  const float4* orow = (const float4*)(out + (size_t)n * DD + lc * 8);
  float4 p0 = orow[0], p1 = orow[1];
  float c[8];
  c[0] = m[0] + b0.x + p0.x; c[1] = m[1] + b0.y + p0.y;
  c[2] = m[2] + b0.z + p0.z; c[3] = m[3] + b0.w + p0.w;
  c[4] = m[4] + b1.x + p1.x; c[5] = m[5] + b1.y + p1.y;
  c[6] = m[6] + b1.z + p1.z; c[7] = m[7] + b1.w + p1.w;
  float ss = c[0] + c[1] + c[2] + c[3] + c[4] + c[5] + c[6] + c[7];
  ss += __shfl_xor(ss, 1); ss += __shfl_xor(ss, 2);
  ss += __shfl_xor(ss, 4); ss += __shfl_xor(ss, 8);
  float mu = ss * (1.f / 128.f);
  float vv = 0.f;
#pragma unroll
  for (int j = 0; j < 8; j++) { float d = c[j] - mu; vv = fmaf(d, d, vv); }
  vv += __shfl_xor(vv, 1); vv += __shfl_xor(vv, 2);
  vv += __shfl_xor(vv, 4); vv += __shfl_xor(vv, 8);
  float inv = rsqrtf(vv * (1.f / 128.f) + LN_EPS);
  const float4* gp = (const float4*)(g + lc * 8);
  const float4* bep = (const float4*)(be + lc * 8);
  float4 g0 = gp[0], g1 = gp[1];
  float4 e0 = bep[0], e1 = bep[1];
  float gv[8] = {g0.x, g0.y, g0.z, g0.w, g1.x, g1.y, g1.z, g1.w};
  float ev[8] = {e0.x, e0.y, e0.z, e0.w, e1.x, e1.y, e1.z, e1.w};
  float o[8];
#pragma unroll
  for (int j = 0; j < 8; j++) {
    float y = (c[j] - mu) * inv * gv[j] + ev[j];
    o[j] = gelu_fast(y);
  }
  if (lane < 16) {
    float4* op = (float4*)(out + (size_t)n * DD + lane * 8);
    op[0] = make_float4(o[0], o[1], o[2], o[3]);
    op[1] = make_float4(o[4], o[5], o[6], o[7]);
  }
}

extern "C" void kernel_launch(void* const* d_in, const int* in_sizes, int n_in,
                              void* d_out, int out_size, void* d_ws, size_t ws_size,
                              hipStream_t stream) {
  const float* feat_host = (const float*)d_in[0];
  const float* feat_flow = (const float*)d_in[1];
  const float* W1  = (const float*)d_in[2];
  const float* al1 = (const float*)d_in[3];
  const float* ar1 = (const float*)d_in[4];
  const float* b1  = (const float*)d_in[5];
  const float* W2  = (const float*)d_in[6];
  const float* al2 = (const float*)d_in[7];
  const float* ar2 = (const float*)d_in[8];
  const float* b2  = (const float*)d_in[9];
  const float* pWh = (const float*)d_in[10];
  const float* pbh = (const float*)d_in[11];
  const float* pWf = (const float*)d_in[12];
  const float* pbf = (const float*)d_in[13];
  const float* gh  = (const float*)d_in[14];
  const float* beh = (const float*)d_in[15];
  const float* gf  = (const float*)d_in[16];
  const float* bef = (const float*)d_in[17];
  const int* e1s = (const int*)d_in[18];
  const int* e1d = (const int*)d_in[19];
  const int* e2s = (const int*)d_in[20];
  const int* e2d = (const int*)d_in[21];

  float* out = (float*)d_out;
  float* host_out = out;                       // [NN,128]
  float* flow_out = out + (size_t)NN * DD;     // [NN,128]

  float* ws = (float*)d_ws;
  size_t off = 0;
  unsigned short* fsb = (unsigned short*)(ws + off); off += (size_t)NN * 256;  // NN x 512 bf16
  short* W1t  = (short*)(ws + off); off += (512 * 256) / 2;
  short* W2t  = (short*)(ws + off); off += (512 * 256) / 2;
  short* pWht = (short*)(ws + off); off += (128 * 256) / 2;
  short* pWft = (short*)(ws + off); off += (128 * 256) / 2;
  float* el1b = ws + off; off += (size_t)NN * HH;
  float* er1b = ws + off; off += (size_t)NN * HH;
  float* el2b = ws + off; off += (size_t)NN * HH;
  float* er2b = ws + off; off += (size_t)NN * HH;
  float* Cbuf = ws + off; off += 4096;
  short* CtH  = (short*)(ws + off); off += 2048;     // 16x256 bf16
  short* CtF  = (short*)(ws + off); off += 2048;
  float* bm   = ws + off; off += 256;          // bm1 | bm2
  float* wexp1 = ws + off; off += (size_t)EE * HH;   // per-slot exp coeffs
  float* wexp2 = ws + off; off += (size_t)EE * HH;
  // CSR
  int* rp1  = (int*)(ws + off);      // NN+1
  int* rp2  = rp1 + (NN + 1);
  int* adj1 = rp2 + (NN + 1);        // EE (src ids)
  int* adj2 = adj1 + EE;
  int* bsum = adj2 + EE;             // 256
  int* cur1 = bsum + 256;            // NN } contiguous memset region (2*NN)
  int* cur2 = cur1 + NN;             // NN }
  off += (size_t)(2 * (NN + 1) + 2 * EE + 256 + 2 * NN + 4);
  // optional bf16 feature copies
  size_t base_bytes = (off + 1024) * sizeof(float);
  size_t featb_bytes = (size_t)NN * KIN * 2 * 2;
  bool use_featb = ws_size >= base_bytes + featb_bytes;
  short* fhb = nullptr;
  short* ffb = nullptr;
  if (use_featb) {
    fhb = (short*)(ws + off); off += (size_t)NN * KIN / 2;
    ffb = (short*)(ws + off); off += (size_t)NN * KIN / 2;
  }

  dim3 blk(256);
  int gx = (NN + 127) / 128;                 // 782 row tiles
  int pm_g = (NN + 63) / 64;                 // prep_mfma blocks (64 rows each)
  int sk_g = (NN + 3) / 4;
  int ag_g = (NN + 3) / 4;
  int ee2_g = (2 * EE + 255) / 256;
  int nn_g = (NN + 255) / 256;

  // ---- prep
  convw<<<512, blk, 0, stream>>>(W1, W2, pWh, pWf, W1t, W2t, pWht, pWft);
  make_c<<<dim3(1, 4), blk, 0, stream>>>(W1, al1, ar1, W2, al2, ar2, Cbuf, CtH, CtF);
  make_bm<<<1, blk, 0, stream>>>(b1, pbf, b2, pbh, bm);
  if (use_featb) {
    prep_mfma<<<dim3(pm_g, 2), blk, 0, stream>>>(
        feat_host, feat_flow, CtH, CtF, fhb, ffb,
        el1b, er2b, er1b, el2b, NN);
  } else {
    skinny8<<<sk_g, blk, 0, stream>>>(feat_host, Cbuf + 0,    Cbuf + 3072, el1b, er2b, NN);
    skinny8<<<sk_g, blk, 0, stream>>>(feat_flow, Cbuf + 1024, Cbuf + 2048, er1b, el2b, NN);
  }

  // ---- CSR + per-edge coeffs (no denominator atomics)
  hipMemsetAsync(cur1, 0, (size_t)2 * NN * sizeof(int), stream);
  hist2<<<ee2_g, blk, 0, stream>>>(e1d, e2d, cur1, cur2);
  scan_chunk<<<dim3(NB_SCAN, 2), blk, 0, stream>>>(cur1, cur2, rp1, rp2, bsum);
  scan_bsum<<<dim3(1, 2), 128, 0, stream>>>(bsum);
  addoff2<<<dim3(nn_g, 2), blk, 0, stream>>>(rp1, rp2, cur1, cur2, bsum);
  fill_s<<<ee2_g, blk, 0, stream>>>(e1s, e1d, e2s, e2d, el1b, er1b, el2b, er2b,
                                    cur1, cur2, adj1, adj2, wexp1, wexp2);

  // ---- relation 1: host -> flow (dst = flow, out = flow_out)
  if (use_featb) {
    mfma_gemm<1><<<gx, blk, 0, stream>>>(ffb, pWft, flow_out, DD, NN, 0, 1);
    mfma_gemm<1><<<gx * 4, blk, 0, stream>>>(fhb, W1t, fsb, HD, NN, 1, 4);
  } else {
    mfma_gemm<0><<<gx, blk, 0, stream>>>(feat_flow, pWft, flow_out, DD, NN, 0, 1);
    mfma_gemm<0><<<gx * 4, blk, 0, stream>>>(feat_host, W1t, fsb, HD, NN, 1, 4);
  }
  agg2<<<ag_g, blk, 0, stream>>>(rp1, adj1, wexp1, fsb, bm, gf, bef, flow_out, NN);

  // ---- relation 2: flow -> host (dst = host, out = host_out)
  if (use_featb) {
    mfma_gemm<1><<<gx, blk, 0, stream>>>(fhb, pWht, host_out, DD, NN, 0, 1);
    mfma_gemm<1><<<gx * 4, blk, 0, stream>>>(ffb, W2t, fsb, HD, NN, 1, 4);
  } else {
    mfma_gemm<0><<<gx, blk, 0, stream>>>(feat_host, pWht, host_out, DD, NN, 0, 1);
    mfma_gemm<0><<<gx * 4, blk, 0, stream>>>(feat_flow, W2t, fsb, HD, NN, 1, 4);
  }
  agg2<<<ag_g, blk, 0, stream>>>(rp2, adj2, wexp2, fsb, bm + 128, gh, beh, host_out, NN);
}

// Round 18
// 449.870 us; speedup vs baseline: 1.0156x; 1.0156x over previous
//
#include <hip/hip_runtime.h>
#include <math.h>

#define NN 100000      // nodes per type
#define EE 200000      // edges per relation
#define HH 4
#define DD 128
#define HD 512         // H*D
#define KIN 256        // input feature dim
#define LN_EPS 1e-5f
#define SLOPE 0.2f
#define NB_SCAN 98     // ceil(NN/1024)

// LDS bank-conflict swizzle for the Cs[2048] table (skinny8 fallback).
#define CSW(a) ((a) ^ (((a) >> 5) & 31))

typedef short bf16x8 __attribute__((ext_vector_type(8)));
typedef unsigned short u16x4 __attribute__((ext_vector_type(4)));
typedef float f32x4 __attribute__((ext_vector_type(4)));

typedef __attribute__((address_space(3))) unsigned int lds_uint;
typedef const __attribute__((address_space(1))) unsigned int glb_uint;

static __device__ __forceinline__ void gload_lds16(const void* g, void* l) {
  __builtin_amdgcn_global_load_lds((glb_uint*)g, (lds_uint*)l, 16, 0, 0);
}

static __device__ __forceinline__ unsigned short f2bf(float x) {
  unsigned int u = __float_as_uint(x);
  u += 0x7fffu + ((u >> 16) & 1u);   // RNE
  return (unsigned short)(u >> 16);
}
static __device__ __forceinline__ float bf_lo(unsigned int u) {
  return __uint_as_float(u << 16);
}
static __device__ __forceinline__ float bf_hi(unsigned int u) {
  return __uint_as_float(u & 0xffff0000u);
}

// Branch-free erf, Abramowitz-Stegun 7.1.26 (max err 1.5e-7).
static __device__ __forceinline__ float erf_fast(float x) {
  float ax = fabsf(x);
  float t = __builtin_amdgcn_rcpf(fmaf(0.3275911f, ax, 1.0f));
  float p = fmaf(1.061405429f, t, -1.453152027f);
  p = fmaf(p, t, 1.421413741f);
  p = fmaf(p, t, -0.284496736f);
  p = fmaf(p, t, 0.254829592f);
  p = p * t;
  float r = 1.0f - p * __expf(-ax * ax);
  return copysignf(r, x);
}
static __device__ __forceinline__ float gelu_fast(float y) {
  return 0.5f * y * (1.0f + erf_fast(y * 0.70710678118f));
}

// ---------------- convert + transpose weights to bf16 [N][K]
__global__ __launch_bounds__(256) void convw(
    const float* __restrict__ W1, const float* __restrict__ W2,
    const float* __restrict__ pWh, const float* __restrict__ pWf,
    short* __restrict__ W1t, short* __restrict__ W2t,
    short* __restrict__ pWht, short* __restrict__ pWft) {
  int idx = blockIdx.x * 256 + threadIdx.x;
  if (idx < 512 * 256) {
    int n = idx >> 8, k = idx & 255;
    W1t[idx] = (short)f2bf(W1[(size_t)k * HD + n]);
    W2t[idx] = (short)f2bf(W2[(size_t)k * HD + n]);
  }
  if (idx < 128 * 256) {
    int n = idx >> 8, k = idx & 255;
    pWht[idx] = (short)f2bf(pWh[(size_t)k * DD + n]);
    pWft[idx] = (short)f2bf(pWf[(size_t)k * DD + n]);
  }
}

// ---------------- build C[k,h] = sum_d W[k,h*128+d]*a[h*128+d]  (f32 + bf16 Ct)
__global__ __launch_bounds__(256) void make_c(
    const float* __restrict__ W1, const float* __restrict__ al1, const float* __restrict__ ar1,
    const float* __restrict__ W2, const float* __restrict__ al2, const float* __restrict__ ar2,
    float* __restrict__ Cout, short* __restrict__ CtH, short* __restrict__ CtF) {
  int which = blockIdx.y;
  const float* W = (which < 2) ? W1 : W2;
  const float* a = (which == 0) ? al1 : (which == 1) ? ar1 : (which == 2) ? al2 : ar2;
  int k = threadIdx.x;
  float* C = Cout + (size_t)which * 1024;
#pragma unroll
  for (int h = 0; h < HH; h++) {
    float s = 0.f;
    for (int d = 0; d < DD; d++) s = fmaf(W[(size_t)k * HD + h * DD + d], a[h * DD + d], s);
    C[k * HH + h] = s;
    short b = (short)f2bf(s);
    if (which == 0)      CtH[h * KIN + k] = b;
    else if (which == 3) CtH[(4 + h) * KIN + k] = b;
    else if (which == 1) CtF[h * KIN + k] = b;
    else                 CtF[(4 + h) * KIN + k] = b;
  }
  if (which == 0) {
#pragma unroll
    for (int j = 0; j < 8; j++) CtH[(8 + j) * KIN + k] = 0;
  } else if (which == 1) {
#pragma unroll
    for (int j = 0; j < 8; j++) CtF[(8 + j) * KIN + k] = 0;
  }
}

// ---------------- bm1[d] = 0.25*sum_h b1 + pbf ; bm2 likewise (b2, pbh)
__global__ __launch_bounds__(256) void make_bm(
    const float* __restrict__ b1, const float* __restrict__ pbf,
    const float* __restrict__ b2, const float* __restrict__ pbh,
    float* __restrict__ bm) {
  int d = threadIdx.x;
  if (d < 128) {
    bm[d] = 0.25f * (b1[d] + b1[128 + d] + b1[256 + d] + b1[384 + d]) + pbf[d];
  } else {
    int dd = d - 128;
    bm[d] = 0.25f * (b2[dd] + b2[128 + dd] + b2[256 + dd] + b2[384 + dd]) + pbh[dd];
  }
}

// ---------------- fused bf16 convert + el/er dots via MFMA, ASYNC staging
// Block = 256 thr (4 waves) = 32 rows. Stage A: global_load_lds stages the
// 32x256 f32 panel into LDS (8 calls/wave, deep vmcnt pipeline). Stage B:
// LDS f32 -> bf16 regs -> coalesced Xb store + swizzled bf16 LDS tile
// (chunk ^ (row&7), same involution on write & read). Stage C: MFMA (2 waves).
__global__ __launch_bounds__(256) void prep_mfma(
    const float* __restrict__ XH, const float* __restrict__ XF,
    const short* __restrict__ CtH, const short* __restrict__ CtF,
    short* __restrict__ XbH, short* __restrict__ XbF,
    float* __restrict__ o1H, float* __restrict__ o2H,
    float* __restrict__ o1F, float* __restrict__ o2F, int M) {
  __shared__ float f32s[32 * 256];  // 32 KB staged panel
  __shared__ short Asm[32 * 256];   // 16 KB bf16 tile
  __shared__ float os[32 * 8];      // 1 KB acc staging
  int which = blockIdx.y;
  const float* X = which ? XF : XH;
  const short* Ct = which ? CtF : CtH;
  short* Xb = which ? XbF : XbH;
  float* o1 = which ? o1F : o1H;
  float* o2 = which ? o2F : o2H;
  int t = threadIdx.x, lane = t & 63, wid = t >> 6;
  int row0 = blockIdx.x * 32;

  // ---- stage A: async stage 32 rows (1 KB each); call c stages row wid*8+c
#pragma unroll
  for (int c = 0; c < 8; c++) {
    int r_loc = wid * 8 + c;
    int grow = row0 + r_loc; if (grow > M - 1) grow = M - 1;
    gload_lds16(X + (size_t)grow * KIN + lane * 4,
                (char*)f32s + r_loc * 1024);
  }
  __syncthreads();   // drains vmcnt

  // ---- stage B: convert; thread t: row r = t>>3, sub j = t&7, 4 chunks c16=j+i*8
  {
    int r = t >> 3, j = t & 7;
    int grow = row0 + r; if (grow > M - 1) grow = M - 1;
#pragma unroll
    for (int i = 0; i < 4; i++) {
      int c16 = j + i * 8;                  // 16B-chunk index (bf16), 8 floats
      const float* fp = f32s + r * 256 + c16 * 8;
      float4 v0 = *(const float4*)fp;
      float4 v1 = *(const float4*)(fp + 4);
      bf16x8 af;
      af[0] = (short)f2bf(v0.x); af[1] = (short)f2bf(v0.y);
      af[2] = (short)f2bf(v0.z); af[3] = (short)f2bf(v0.w);
      af[4] = (short)f2bf(v1.x); af[5] = (short)f2bf(v1.y);
      af[6] = (short)f2bf(v1.z); af[7] = (short)f2bf(v1.w);
      *(bf16x8*)(Xb + (size_t)grow * KIN + c16 * 8) = af;  // coalesced (dup rows benign)
      int swc = c16 ^ (r & 7);
      *(bf16x8*)((char*)Asm + r * 512 + swc * 16) = af;
    }
  }
  // B fragments (global, L2-hot)
  int lr = lane & 15, lk = lane >> 4;
  bf16x8 bfrag[8];
#pragma unroll
  for (int kc = 0; kc < 8; kc++)
    bfrag[kc] = *(const bf16x8*)(Ct + lr * KIN + kc * 32 + lk * 8);
  __syncthreads();

  // ---- stage C: MFMA, waves 0-1 handle rows wid*16..+16
  if (wid < 2) {
    int lrow = wid * 16 + lr;
    f32x4 acc = (f32x4){0.f, 0.f, 0.f, 0.f};
#pragma unroll
    for (int kc = 0; kc < 8; kc++) {
      int chunk = (lk + kc * 4) ^ (lrow & 7);
      bf16x8 af = *(bf16x8*)((char*)Asm + lrow * 512 + chunk * 16);
      acc = __builtin_amdgcn_mfma_f32_16x16x32_bf16(af, bfrag[kc], acc, 0, 0, 0);
    }
    if (lr < 8) {
#pragma unroll
      for (int r = 0; r < 4; r++)
        os[(wid * 16 + lk * 4 + r) * 8 + lr] = acc[r];
    }
  }
  __syncthreads();

  // ---- epilogue: coalesced o1/o2 writes
  if (t < 32) {
    int row = row0 + t;
    if (row < M)
      *(float4*)(o1 + (size_t)row * HH) =
          make_float4(os[t * 8 + 0], os[t * 8 + 1], os[t * 8 + 2], os[t * 8 + 3]);
  } else if (t >= 64 && t < 96) {
    int j = t - 64;
    int row = row0 + j;
    if (row < M)
      *(float4*)(o2 + (size_t)row * HH) =
          make_float4(os[j * 8 + 4], os[j * 8 + 5], os[j * 8 + 6], os[j * 8 + 7]);
  }
}

// ---------------- fallback skinny (no bf16 feature copy)
__global__ __launch_bounds__(256) void skinny8(
    const float* __restrict__ X, const float* __restrict__ C1, const float* __restrict__ C2,
    float* __restrict__ o1, float* __restrict__ o2, int M) {
  __shared__ float Cs[KIN * 8];
  int tid = threadIdx.x;
  for (int i = tid; i < KIN * 4; i += 256) {
    int k = i >> 2, h = i & 3;
    Cs[CSW(k * 8 + h)] = C1[i];
    Cs[CSW(k * 8 + 4 + h)] = C2[i];
  }
  __syncthreads();
  int wave = tid >> 6, lane = tid & 63;
  int n = blockIdx.x * 4 + wave;
  if (n >= M) return;
  float4 xv = ((const float4*)(X + (size_t)n * KIN))[lane];
  float xs[4] = {xv.x, xv.y, xv.z, xv.w};
  float acc[8] = {0.f, 0.f, 0.f, 0.f, 0.f, 0.f, 0.f, 0.f};
#pragma unroll
  for (int j = 0; j < 4; j++) {
    int k = lane * 4 + j;
#pragma unroll
    for (int t = 0; t < 8; t++) acc[t] = fmaf(xs[j], Cs[CSW(k * 8 + t)], acc[t]);
  }
#pragma unroll
  for (int off = 32; off >= 1; off >>= 1)
#pragma unroll
    for (int t = 0; t < 8; t++) acc[t] += __shfl_xor(acc[t], off);
  if (lane == 0) {
#pragma unroll
    for (int h = 0; h < HH; h++) {
      o1[(size_t)n * HH + h] = acc[h];
      o2[(size_t)n * HH + h] = acc[4 + h];
    }
  }
}

// ---------------- CSR build ----------------
__global__ __launch_bounds__(256) void hist2(
    const int* __restrict__ d1, const int* __restrict__ d2,
    int* __restrict__ c1, int* __restrict__ c2) {
  int gid = blockIdx.x * 256 + threadIdx.x;
  if (gid < EE) atomicAdd(&c1[d1[gid]], 1);
  else if (gid < 2 * EE) atomicAdd(&c2[d2[gid - EE]], 1);
}

__global__ __launch_bounds__(256) void scan_chunk(
    const int* __restrict__ c1, const int* __restrict__ c2,
    int* __restrict__ rp1, int* __restrict__ rp2, int* __restrict__ bsum) {
  int rel = blockIdx.y;
  const int* counts = rel ? c2 : c1;
  int* rowptr = rel ? rp2 : rp1;
  int* bs = bsum + rel * 128;
  __shared__ int sd[256];
  int tid = threadIdx.x;
  int base = blockIdx.x * 1024 + tid * 4;
  int c[4];
#pragma unroll
  for (int j = 0; j < 4; j++) c[j] = (base + j < NN) ? counts[base + j] : 0;
  int tot = c[0] + c[1] + c[2] + c[3];
  sd[tid] = tot; __syncthreads();
  for (int o = 1; o < 256; o <<= 1) {
    int v = (tid >= o) ? sd[tid - o] : 0;
    __syncthreads();
    sd[tid] += v;
    __syncthreads();
  }
  int excl = sd[tid] - tot;
  int run = excl;
#pragma unroll
  for (int j = 0; j < 4; j++) {
    if (base + j < NN) rowptr[base + j] = run;
    run += c[j];
  }
  if (tid == 255) bs[blockIdx.x] = sd[255];
}

__global__ __launch_bounds__(128) void scan_bsum(int* __restrict__ bsum) {
  int rel = blockIdx.y;
  int* bs = bsum + rel * 128;
  __shared__ int sd[128];
  int tid = threadIdx.x;
  int v = (tid < NB_SCAN) ? bs[tid] : 0;
  sd[tid] = v; __syncthreads();
  for (int o = 1; o < 128; o <<= 1) {
    int t = (tid >= o) ? sd[tid - o] : 0;
    __syncthreads();
    sd[tid] += t;
    __syncthreads();
  }
  bs[tid] = sd[tid] - v;
}

__global__ __launch_bounds__(256) void addoff2(
    int* __restrict__ rp1, int* __restrict__ rp2,
    int* __restrict__ cur1, int* __restrict__ cur2,
    const int* __restrict__ bsum) {
  int rel = blockIdx.y;
  int* rowptr = rel ? rp2 : rp1;
  int* cur = rel ? cur2 : cur1;
  const int* bs = bsum + rel * 128;
  int i = blockIdx.x * 256 + threadIdx.x;
  if (i < NN) {
    int r = rowptr[i] + bs[i >> 10];
    rowptr[i] = r;
    cur[i] = r;
  }
  if (i == 0) rowptr[NN] = EE;
}

// ---------------- fill CSR: adjacency only (exp moved into agg2)
__global__ __launch_bounds__(256) void fill_s(
    const int* __restrict__ e1s, const int* __restrict__ e1d,
    const int* __restrict__ e2s, const int* __restrict__ e2d,
    int* __restrict__ cur1, int* __restrict__ cur2,
    int* __restrict__ adj1, int* __restrict__ adj2) {
  int gid = blockIdx.x * 256 + threadIdx.x;
  if (gid >= 2 * EE) return;
  int rel = (gid >= EE);
  int e = rel ? gid - EE : gid;
  const int* srcp = rel ? e2s : e1s;
  const int* dstp = rel ? e2d : e1d;
  int* cur = rel ? cur2 : cur1;
  int* adj = rel ? adj2 : adj1;
  int si = srcp[e], di = dstp[e];
  int p = atomicAdd(&cur[di], 1);
  adj[p] = si;
}

// ---------------- MFMA GEMM: C[M x N] = A[M x 256] @ Wt[N x 256]^T
template <int ABF>
__global__ __launch_bounds__(256) void mfma_gemm(
    const void* __restrict__ Av, const short* __restrict__ Wt,
    void* __restrict__ Cout, int ldC, int M, int write_bf, int ncol) {
  __shared__ short As[128 * 64];
  __shared__ short Bs[128 * 64];
  int nwg = gridDim.x;
  int q = nwg >> 3, r = nwg & 7;
  int xcd = blockIdx.x & 7, seq = blockIdx.x >> 3;
  int lid = (xcd < r) ? (xcd * (q + 1) + seq) : (r * (q + 1) + (xcd - r) * q + seq);
  int row0 = (lid / ncol) * 128;
  int col0 = (lid % ncol) * 128;

  int tid = threadIdx.x;
  int lane = tid & 63, wid = tid >> 6;
  int wm = wid >> 1, wn = wid & 1;

  f32x4 acc[4][4];
#pragma unroll
  for (int i = 0; i < 4; i++)
#pragma unroll
    for (int j = 0; j < 4; j++) acc[i][j] = (f32x4){0.f, 0.f, 0.f, 0.f};

  int am = tid >> 1;
  int akh = (tid & 1) * 32;
  bool arow_ok = (row0 + am) < M;

  for (int k0 = 0; k0 < KIN; k0 += 64) {
    __syncthreads();
    if (ABF) {
      int rr8 = lane >> 3;
      int bby = (lane & 7) * 16;
#pragma unroll
      for (int c2 = 0; c2 < 4; c2++) {
        int rr = wid * 32 + c2 * 8 + rr8;
        int rg = row0 + rr; if (rg > M - 1) rg = M - 1;
        int sb = bby ^ ((rr & 7) << 4);
        gload_lds16((const char*)Av + (size_t)rg * (KIN * 2) + k0 * 2 + sb,
                    (char*)As + wid * 4096 + c2 * 1024);
      }
#pragma unroll
      for (int c2 = 0; c2 < 4; c2++) {
        int rr = wid * 32 + c2 * 8 + rr8;
        int sb = bby ^ ((rr & 7) << 4);
        gload_lds16((const char*)Wt + (size_t)(col0 + rr) * (KIN * 2) + k0 * 2 + sb,
                    (char*)Bs + wid * 4096 + c2 * 1024);
      }
    } else {
      const float* xp = (const float*)Av + (size_t)(row0 + am) * KIN + k0 + akh;
#pragma unroll
      for (int c = 0; c < 4; c++) {
        float4 v0, v1;
        if (arow_ok) {
          v0 = *(const float4*)(xp + c * 8);
          v1 = *(const float4*)(xp + c * 8 + 4);
        } else {
          v0 = make_float4(0.f, 0.f, 0.f, 0.f);
          v1 = v0;
        }
        bf16x8 pk;
        pk[0] = (short)f2bf(v0.x); pk[1] = (short)f2bf(v0.y);
        pk[2] = (short)f2bf(v0.z); pk[3] = (short)f2bf(v0.w);
        pk[4] = (short)f2bf(v1.x); pk[5] = (short)f2bf(v1.y);
        pk[6] = (short)f2bf(v1.z); pk[7] = (short)f2bf(v1.w);
        int kc = akh + c * 8;
        int ad = (am * 128 + kc * 2) ^ ((am & 7) << 4);
        *(bf16x8*)((char*)As + ad) = pk;
      }
      int bn = tid >> 1;
      int bkh = (tid & 1) * 32;
      const short* wp = Wt + (size_t)(col0 + bn) * KIN + k0 + bkh;
#pragma unroll
      for (int c = 0; c < 4; c++) {
        bf16x8 pv = *(const bf16x8*)(wp + c * 8);
        int kc = bkh + c * 8;
        int bd = (bn * 128 + kc * 2) ^ ((bn & 7) << 4);
        *(bf16x8*)((char*)Bs + bd) = pv;
      }
    }
    __syncthreads();
#pragma unroll
    for (int ks = 0; ks < 2; ks++) {
      int kb = ks * 32 + (lane >> 4) * 8;
      bf16x8 af[4], bfv[4];
#pragma unroll
      for (int mf = 0; mf < 4; mf++) {
        int rr = wm * 64 + mf * 16 + (lane & 15);
        int ad = (rr * 128 + kb * 2) ^ ((rr & 7) << 4);
        af[mf] = *(bf16x8*)((char*)As + ad);
      }
#pragma unroll
      for (int nf = 0; nf < 4; nf++) {
        int cc = wn * 64 + nf * 16 + (lane & 15);
        int bd = (cc * 128 + kb * 2) ^ ((cc & 7) << 4);
        bfv[nf] = *(bf16x8*)((char*)Bs + bd);
      }
#pragma unroll
      for (int mf = 0; mf < 4; mf++)
#pragma unroll
        for (int nf = 0; nf < 4; nf++)
          acc[mf][nf] = __builtin_amdgcn_mfma_f32_16x16x32_bf16(af[mf], bfv[nf], acc[mf][nf], 0, 0, 0);
    }
  }
  int lr = lane >> 4, lc = lane & 15;
#pragma unroll
  for (int mf = 0; mf < 4; mf++) {
#pragma unroll
    for (int r4 = 0; r4 < 4; r4++) {
      int row = row0 + wm * 64 + mf * 16 + lr * 4 + r4;
      if (row < M) {
#pragma unroll
        for (int nf = 0; nf < 4; nf++) {
          int col = col0 + wn * 64 + nf * 16 + lc;
          float v = acc[mf][nf][r4];
          if (write_bf) ((unsigned short*)Cout)[(size_t)row * ldC + col] = f2bf(v);
          else ((float*)Cout)[(size_t)row * ldC + col] = v;
        }
      }
    }
  }
}

// ---------------- single-pass agg + softmax(inline exp) + mean + residual + LN + GELU
// One wave/dst. Lane l: head lh=l>>4, dims 8*(l&15)..+8. Coefficient computed
// inline: w = exp(leaky(el[src,lh] + er[n,lh])); denominator folded at end.
__global__ __launch_bounds__(256) void agg2(
    const int* __restrict__ rowptr, const int* __restrict__ adj,
    const float* __restrict__ el, const float* __restrict__ er,
    const unsigned short* __restrict__ fsb,
    const float* __restrict__ bm,
    const float* __restrict__ g, const float* __restrict__ be,
    float* __restrict__ out, int M) {
  int wave = threadIdx.x >> 6, lane = threadIdx.x & 63;
  int n = blockIdx.x * 4 + wave;
  if (n >= M) return;
  int beg = rowptr[n], end = rowptr[n + 1];
  int lh = lane >> 4, lc = lane & 15;
  float ern = er[(size_t)n * HH + lh];
  float sh = 0.f;
  float m[8] = {0.f, 0.f, 0.f, 0.f, 0.f, 0.f, 0.f, 0.f};
  for (int t = beg; t < end; t++) {
    int si = adj[t];
    float v = el[(size_t)si * HH + lh] + ern;
    v = v > 0.f ? v : SLOPE * v;
    float wh = __expf(v);
    sh += wh;
    uint4 u = *(const uint4*)(fsb + (size_t)si * HD + lane * 8);
    m[0] = fmaf(wh, bf_lo(u.x), m[0]); m[1] = fmaf(wh, bf_hi(u.x), m[1]);
    m[2] = fmaf(wh, bf_lo(u.y), m[2]); m[3] = fmaf(wh, bf_hi(u.y), m[3]);
    m[4] = fmaf(wh, bf_lo(u.z), m[4]); m[5] = fmaf(wh, bf_hi(u.z), m[5]);
    m[6] = fmaf(wh, bf_lo(u.w), m[6]); m[7] = fmaf(wh, bf_hi(u.w), m[7]);
  }
  float rsh = sh > 0.f ? 0.25f / sh : 0.f;
#pragma unroll
  for (int j = 0; j < 8; j++) m[j] *= rsh;
#pragma unroll
  for (int j = 0; j < 8; j++) {
    m[j] += __shfl_xor(m[j], 16);
    m[j] += __shfl_xor(m[j], 32);
  }
  const float4* bmp = (const float4*)(bm + lc * 8);
  float4 b0 = bmp[0], b1 = bmp[1];
  const float4* orow = (const float4*)(out + (size_t)n * DD + lc * 8);
  float4 p0 = orow[0], p1 = orow[1];
  float c[8];
  c[0] = m[0] + b0.x + p0.x; c[1] = m[1] + b0.y + p0.y;
  c[2] = m[2] + b0.z + p0.z; c[3] = m[3] + b0.w + p0.w;
  c[4] = m[4] + b1.x + p1.x; c[5] = m[5] + b1.y + p1.y;
  c[6] = m[6] + b1.z + p1.z; c[7] = m[7] + b1.w + p1.w;
  float ss = c[0] + c[1] + c[2] + c[3] + c[4] + c[5] + c[6] + c[7];
  ss += __shfl_xor(ss, 1); ss += __shfl_xor(ss, 2);
  ss += __shfl_xor(ss, 4); ss += __shfl_xor(ss, 8);
  float mu = ss * (1.f / 128.f);
  float vv = 0.f;
#pragma unroll
  for (int j = 0; j < 8; j++) { float d = c[j] - mu; vv = fmaf(d, d, vv); }
  vv += __shfl_xor(vv, 1); vv += __shfl_xor(vv, 2);
  vv += __shfl_xor(vv, 4); vv += __shfl_xor(vv, 8);
  float inv = rsqrtf(vv * (1.f / 128.f) + LN_EPS);
  const float4* gp = (const float4*)(g + lc * 8);
  const float4* bep = (const float4*)(be + lc * 8);
  float4 g0 = gp[0], g1 = gp[1];
  float4 e0 = bep[0], e1 = bep[1];
  float gv[8] = {g0.x, g0.y, g0.z, g0.w, g1.x, g1.y, g1.z, g1.w};
  float ev[8] = {e0.x, e0.y, e0.z, e0.w, e1.x, e1.y, e1.z, e1.w};
  float o[8];
#pragma unroll
  for (int j = 0; j < 8; j++) {
    float y = (c[j] - mu) * inv * gv[j] + ev[j];
    o[j] = gelu_fast(y);
  }
  if (lane < 16) {
    float4* op = (float4*)(out + (size_t)n * DD + lane * 8);
    op[0] = make_float4(o[0], o[1], o[2], o[3]);
    op[1] = make_float4(o[4], o[5], o[6], o[7]);
  }
}

extern "C" void kernel_launch(void* const* d_in, const int* in_sizes, int n_in,
                              void* d_out, int out_size, void* d_ws, size_t ws_size,
                              hipStream_t stream) {
  const float* feat_host = (const float*)d_in[0];
  const float* feat_flow = (const float*)d_in[1];
  const float* W1  = (const float*)d_in[2];
  const float* al1 = (const float*)d_in[3];
  const float* ar1 = (const float*)d_in[4];
  const float* b1  = (const float*)d_in[5];
  const float* W2  = (const float*)d_in[6];
  const float* al2 = (const float*)d_in[7];
  const float* ar2 = (const float*)d_in[8];
  const float* b2  = (const float*)d_in[9];
  const float* pWh = (const float*)d_in[10];
  const float* pbh = (const float*)d_in[11];
  const float* pWf = (const float*)d_in[12];
  const float* pbf = (const float*)d_in[13];
  const float* gh  = (const float*)d_in[14];
  const float* beh = (const float*)d_in[15];
  const float* gf  = (const float*)d_in[16];
  const float* bef = (const float*)d_in[17];
  const int* e1s = (const int*)d_in[18];
  const int* e1d = (const int*)d_in[19];
  const int* e2s = (const int*)d_in[20];
  const int* e2d = (const int*)d_in[21];

  float* out = (float*)d_out;
  float* host_out = out;                       // [NN,128]
  float* flow_out = out + (size_t)NN * DD;     // [NN,128]

  float* ws = (float*)d_ws;
  size_t off = 0;
  unsigned short* fsb = (unsigned short*)(ws + off); off += (size_t)NN * 256;  // NN x 512 bf16
  short* W1t  = (short*)(ws + off); off += (512 * 256) / 2;
  short* W2t  = (short*)(ws + off); off += (512 * 256) / 2;
  short* pWht = (short*)(ws + off); off += (128 * 256) / 2;
  short* pWft = (short*)(ws + off); off += (128 * 256) / 2;
  float* el1b = ws + off; off += (size_t)NN * HH;
  float* er1b = ws + off; off += (size_t)NN * HH;
  float* el2b = ws + off; off += (size_t)NN * HH;
  float* er2b = ws + off; off += (size_t)NN * HH;
  float* Cbuf = ws + off; off += 4096;
  short* CtH  = (short*)(ws + off); off += 2048;     // 16x256 bf16
  short* CtF  = (short*)(ws + off); off += 2048;
  float* bm   = ws + off; off += 256;          // bm1 | bm2
  // CSR
  int* rp1  = (int*)(ws + off);      // NN+1
  int* rp2  = rp1 + (NN + 1);
  int* adj1 = rp2 + (NN + 1);        // EE (src ids)
  int* adj2 = adj1 + EE;
  int* bsum = adj2 + EE;             // 256
  int* cur1 = bsum + 256;            // NN } contiguous memset region (2*NN)
  int* cur2 = cur1 + NN;             // NN }
  off += (size_t)(2 * (NN + 1) + 2 * EE + 256 + 2 * NN + 4);
  // optional bf16 feature copies
  size_t base_bytes = (off + 1024) * sizeof(float);
  size_t featb_bytes = (size_t)NN * KIN * 2 * 2;
  bool use_featb = ws_size >= base_bytes + featb_bytes;
  short* fhb = nullptr;
  short* ffb = nullptr;
  if (use_featb) {
    fhb = (short*)(ws + off); off += (size_t)NN * KIN / 2;
    ffb = (short*)(ws + off); off += (size_t)NN * KIN / 2;
  }

  dim3 blk(256);
  int gx = (NN + 127) / 128;                 // 782 row tiles
  int pm_g = (NN + 31) / 32;                 // prep_mfma blocks (32 rows each)
  int sk_g = (NN + 3) / 4;
  int ag_g = (NN + 3) / 4;
  int ee2_g = (2 * EE + 255) / 256;
  int nn_g = (NN + 255) / 256;

  // ---- prep
  convw<<<512, blk, 0, stream>>>(W1, W2, pWh, pWf, W1t, W2t, pWht, pWft);
  make_c<<<dim3(1, 4), blk, 0, stream>>>(W1, al1, ar1, W2, al2, ar2, Cbuf, CtH, CtF);
  make_bm<<<1, blk, 0, stream>>>(b1, pbf, b2, pbh, bm);
  if (use_featb) {
    prep_mfma<<<dim3(pm_g, 2), blk, 0, stream>>>(
        feat_host, feat_flow, CtH, CtF, fhb, ffb,
        el1b, er2b, er1b, el2b, NN);
  } else {
    skinny8<<<sk_g, blk, 0, stream>>>(feat_host, Cbuf + 0,    Cbuf + 3072, el1b, er2b, NN);
    skinny8<<<sk_g, blk, 0, stream>>>(feat_flow, Cbuf + 1024, Cbuf + 2048, er1b, el2b, NN);
  }

  // ---- CSR (adjacency only; exp moved into agg2)
  hipMemsetAsync(cur1, 0, (size_t)2 * NN * sizeof(int), stream);
  hist2<<<ee2_g, blk, 0, stream>>>(e1d, e2d, cur1, cur2);
  scan_chunk<<<dim3(NB_SCAN, 2), blk, 0, stream>>>(cur1, cur2, rp1, rp2, bsum);
  scan_bsum<<<dim3(1, 2), 128, 0, stream>>>(bsum);
  addoff2<<<dim3(nn_g, 2), blk, 0, stream>>>(rp1, rp2, cur1, cur2, bsum);
  fill_s<<<ee2_g, blk, 0, stream>>>(e1s, e1d, e2s, e2d, cur1, cur2, adj1, adj2);

  // ---- relation 1: host -> flow (dst = flow, out = flow_out)
  if (use_featb) {
    mfma_gemm<1><<<gx, blk, 0, stream>>>(ffb, pWft, flow_out, DD, NN, 0, 1);
    mfma_gemm<1><<<gx * 4, blk, 0, stream>>>(fhb, W1t, fsb, HD, NN, 1, 4);
  } else {
    mfma_gemm<0><<<gx, blk, 0, stream>>>(feat_flow, pWft, flow_out, DD, NN, 0, 1);
    mfma_gemm<0><<<gx * 4, blk, 0, stream>>>(feat_host, W1t, fsb, HD, NN, 1, 4);
  }
  agg2<<<ag_g, blk, 0, stream>>>(rp1, adj1, el1b, er1b, fsb, bm, gf, bef, flow_out, NN);

  // ---- relation 2: flow -> host (dst = host, out = host_out)
  if (use_featb) {
    mfma_gemm<1><<<gx, blk, 0, stream>>>(fhb, pWht, host_out, DD, NN, 0, 1);
    mfma_gemm<1><<<gx * 4, blk, 0, stream>>>(ffb, W2t, fsb, HD, NN, 1, 4);
  } else {
    mfma_gemm<0><<<gx, blk, 0, stream>>>(feat_host, pWht, host_out, DD, NN, 0, 1);
    mfma_gemm<0><<<gx * 4, blk, 0, stream>>>(feat_flow, W2t, fsb, HD, NN, 1, 4);
  }
  agg2<<<ag_g, blk, 0, stream>>>(rp2, adj2, el2b, er2b, fsb, bm + 128, gh, beh, host_out, NN);
}